// Round 10
// baseline (196.769 us; speedup 1.0000x reference)
//
#include <hip/hip_runtime.h>
#include <hip/hip_bf16.h>

// Problem geometry
#define NB   16
#define C0   128
#define HH   44
#define WW   144
#define HW   (HH * WW)        // 6336
#define NPOS (NB * HW)        // 101376
#define SC   8
#define WOUT (WW * SC)        // 1152
#define HOUT (HH * SC)        // 352
#define PI_F 3.1415926535f

// DIAGNOSTIC ROUND: the body below runs REP times (idempotent — identical
// writes each pass). REP=2 lifts the kernel above the 41 µs harness fills so
// rocprof's top-5 finally shows its counters. Revert to REP=1 after reading.
#define REP 2

typedef __attribute__((ext_vector_type(8)))  short bf8;   // 8 bf16 (A/B frag, 4 VGPR)
typedef __attribute__((ext_vector_type(4)))  float f4;
typedef __attribute__((ext_vector_type(16))) float f16v;  // 32x32 C/D frag (16 AGPR)
typedef unsigned short ushort_t;

// frag-exact bf16 weight layout in ws (ushort elements), 32x32x16 B-frags:
//   conv0: 16 chunks (t*8+s) x [64 lanes][8]   -> 8192
//   conv1:  4 chunks (s)     x [64 lanes][8]   -> 2048
//   conv2:  2 chunks (s)     x [64 lanes][8]   -> 1024  (N padded 16->32, zeros)
#define F0 0
#define F1 8192
#define F2 10240
#define NWT 11264

__device__ __forceinline__ unsigned f2bf(float f) {
    union { float f; unsigned u; } v; v.f = f;
    unsigned r = v.u + 0x7FFFu + ((v.u >> 16) & 1u);     // RNE
    return r >> 16;
}
__device__ __forceinline__ float eluf(float x) {
    return x > 0.f ? x : (__expf(x) - 1.f);
}
__device__ __forceinline__ float sigmoidf(float x) {
    return 1.f / (1.f + __expf(-x));
}
// C/D row map for 32x32 MFMA: reg r, k-group g -> position row
__device__ __forceinline__ int crow(int r, int g) {
    return (r & 3) + 8 * (r >> 2) + 4 * g;
}

// ---- prep: pack w0/w1/w2 into 32x32x16 B-fragment order (bf16) ----
__global__ void prep_w(const float* __restrict__ w0, const float* __restrict__ w1,
                       const float* __restrict__ w2, ushort_t* __restrict__ ws) {
    int i = blockIdx.x * 256 + (int)threadIdx.x;
    int j = i & 7, lane = (i >> 3) & 63;
    int n = lane & 31, g = lane >> 5;
    if (i < 8192) {
        int c = i >> 9;                       // c = t*8 + s
        int s = c & 7, t = c >> 3;
        ws[F0 + i] = (ushort_t)f2bf(w0[(t * 32 + n) * 128 + s * 16 + g * 8 + j]);
    } else if (i < 10240) {
        int i2 = i - 8192;
        int s = i2 >> 9;                      // 0..3
        ws[F1 + i2] = (ushort_t)f2bf(w1[n * 64 + s * 16 + g * 8 + j]);
    } else if (i < NWT) {
        int i2 = i - 10240;
        int s = i2 >> 9;                      // 0..1
        ws[F2 + i2] = (n < 16) ? (ushort_t)f2bf(w2[n * 32 + s * 16 + g * 8 + j])
                               : (ushort_t)0;
    }
}

// One wave = 32 consecutive positions via 32x32x16 bf16 MFMA. Identical to
// round-9 structure; body repeated REP times for instrumentation.
__global__ __launch_bounds__(256, 3)
void lpg32(const float* __restrict__ x, const ushort_t* __restrict__ wsb,
           const float* __restrict__ b0, const float* __restrict__ b1,
           const float* __restrict__ b2, const float* __restrict__ b3,
           const float* __restrict__ w3, const float* __restrict__ w4,
           const float* __restrict__ b4,
           const float* __restrict__ wc, const float* __restrict__ bc,
           float* __restrict__ out) {
    __shared__ __align__(16) ushort_t hb1s[4][2304];   // [pos32][64+8] bf16
    __shared__ __align__(16) ushort_t hb2s[4][1280];   // [pos32][32+8] bf16
    __shared__ __align__(16) float    hb3s[4][640];    // [pos32][16+4] fp32

    const int tid  = (int)threadIdx.x;
    const int lane = tid & 63;
    const int wid  = tid >> 6;
    const int m    = lane & 31;          // position-in-tile / C-col channel
    const int g    = lane >> 5;          // k-group 0/1

    const int pm  = blockIdx.x * 128 + wid * 32 + m;   // this lane's position
    const int bm  = pm / HW;
    const int hwm = pm - bm * HW;
    const float* xb = x + (size_t)bm * (C0 * HW) + hwm;

#pragma unroll 1
    for (int rep = 0; rep < REP; ++rep) {
    // ---- conv0: 128 -> 64, A loaded per K-step (8 ch), 2 N-tiles x 8 K ----
    bf8 A[8];
#pragma unroll
    for (int s = 0; s < 8; ++s) {
        float xr[8];
#pragma unroll
        for (int j = 0; j < 8; ++j)
            xr[j] = xb[(s * 16 + g * 8 + j) * HW];     // 2 full lines / instr
        bf8 a;
#pragma unroll
        for (int j = 0; j < 8; j += 2) {
            __hip_bfloat162 pck = __float22bfloat162_rn(make_float2(xr[j], xr[j + 1]));
            union { __hip_bfloat162 b; short s2[2]; } u; u.b = pck;
            a[j] = u.s2[0]; a[j + 1] = u.s2[1];
        }
        A[s] = a;
    }

    f16v acc0, acc1;
    {
        const float bb0 = b0[m], bb1 = b0[32 + m];
#pragma unroll
        for (int r = 0; r < 16; ++r) { acc0[r] = bb0; acc1[r] = bb1; }
    }
#pragma unroll
    for (int s = 0; s < 8; ++s) {
        bf8 B = *(const bf8*)(wsb + F0 + (0 * 8 + s) * 512 + lane * 8);
        acc0 = __builtin_amdgcn_mfma_f32_32x32x16_bf16(A[s], B, acc0, 0, 0, 0);
    }
#pragma unroll
    for (int s = 0; s < 8; ++s) {
        bf8 B = *(const bf8*)(wsb + F0 + (1 * 8 + s) * 512 + lane * 8);
        acc1 = __builtin_amdgcn_mfma_f32_32x32x16_bf16(A[s], B, acc1, 0, 0, 0);
    }

    // ELU + scatter C-layout -> h1[pos][ch] bf16 (ch = t*32 + m, row = crow)
    ushort_t* h1p = &hb1s[wid][0];
#pragma unroll
    for (int r = 0; r < 16; ++r) {
        const int row = crow(r, g);
        h1p[row * 72 + m]      = (ushort_t)f2bf(eluf(acc0[r]));
        h1p[row * 72 + 32 + m] = (ushort_t)f2bf(eluf(acc1[r]));
    }

    // ---- conv1: 64 -> 32, 4 K-steps ----
    bf8 A1[4];
#pragma unroll
    for (int s = 0; s < 4; ++s)
        A1[s] = *(const bf8*)(h1p + m * 72 + s * 16 + g * 8);
    f16v c1;
    {
        const float bb = b1[m];
#pragma unroll
        for (int r = 0; r < 16; ++r) c1[r] = bb;
    }
#pragma unroll
    for (int s = 0; s < 4; ++s) {
        bf8 B = *(const bf8*)(wsb + F1 + s * 512 + lane * 8);
        c1 = __builtin_amdgcn_mfma_f32_32x32x16_bf16(A1[s], B, c1, 0, 0, 0);
    }
    ushort_t* h2p = &hb2s[wid][0];
#pragma unroll
    for (int r = 0; r < 16; ++r)
        h2p[crow(r, g) * 40 + m] = (ushort_t)f2bf(eluf(c1[r]));

    // ---- conv2: 32 -> 16 (N padded to 32; cols 16..31 are zero-weight) ----
    bf8 A2[2];
#pragma unroll
    for (int s = 0; s < 2; ++s)
        A2[s] = *(const bf8*)(h2p + m * 40 + s * 16 + g * 8);
    f16v c2;
    {
        const float bb = (m < 16) ? b2[m & 15] : 0.f;
#pragma unroll
        for (int r = 0; r < 16; ++r) c2[r] = bb;
    }
#pragma unroll
    for (int s = 0; s < 2; ++s) {
        bf8 B = *(const bf8*)(wsb + F2 + s * 512 + lane * 8);
        c2 = __builtin_amdgcn_mfma_f32_32x32x16_bf16(A2[s], B, c2, 0, 0, 0);
    }
    float* h3p = &hb3s[wid][0];
    if (m < 16) {
#pragma unroll
        for (int r = 0; r < 16; ++r)
            h3p[crow(r, g) * 20 + m] = eluf(c2[r]);
    }

    // ---- tail: lane handles pos m (2x redundant across g) ----
    float h3[16];
#pragma unroll
    for (int i = 0; i < 4; ++i) {
        f4 v = *(const f4*)(h3p + m * 20 + i * 4);
        h3[4 * i + 0] = v[0]; h3[4 * i + 1] = v[1];
        h3[4 * i + 2] = v[2]; h3[4 * i + 3] = v[3];
    }

    float h4v[8];
#pragma unroll
    for (int o = 0; o < 8; ++o) {
        float a = b3[o];                              // uniform -> s_load
#pragma unroll
        for (int c = 0; c < 16; ++c) a = fmaf(h3[c], w3[o * 16 + c], a);
        h4v[o] = eluf(a);
    }
    float h5v[4];
#pragma unroll
    for (int o = 0; o < 4; ++o) {
        float a = b4[o];
#pragma unroll
        for (int c = 0; c < 8; ++c) a = fmaf(h4v[c], w4[o * 8 + c], a);
        h5v[o] = a;                                   // no activation
    }
    float y0 = bc[0], y1 = bc[1], y2 = bc[2];
#pragma unroll
    for (int c = 0; c < 4; ++c) {
        y0 = fmaf(h5v[c], wc[0 * 4 + c], y0);
        y1 = fmaf(h5v[c], wc[1 * 4 + c], y1);
        y2 = fmaf(h5v[c], wc[2 * 4 + c], y2);
    }

    const float theta = sigmoidf(y0) * (PI_F / 6.0f);
    const float phi   = sigmoidf(y1) * (PI_F * 2.0f);
    const float dist  = sigmoidf(y2) * 81.0f;
    const float st = __sinf(theta), ct = __cosf(theta);
    const float sp = __sinf(phi),   cp = __cosf(phi);
    float nx = st * cp, ny = st * sp, nz = ct;
    const float inv = rsqrtf(fmaxf(nx * nx + ny * ny + nz * nz, 1e-24f));
    nx *= inv; ny *= inv; nz *= inv;

    // ---- 8x8 upsample: lane g writes rows 4g..4g+3 of its position ----
    const int hh = hwm / WW;
    const int wp = hwm - hh * WW;
    float* op = out + ((size_t)bm * HOUT + (size_t)hh * SC) * WOUT + (size_t)wp * SC;

    float nxu[8];
#pragma unroll
    for (int j = 0; j < 8; ++j) nxu[j] = nx * ((j - 3.5f) * 0.125f);

#pragma unroll
    for (int ii = 0; ii < 4; ++ii) {
        const int i = g * 4 + ii;
        const float den0 = fmaf(ny, (i - 3.5f) * 0.125f, nz);
        float d[8];
#pragma unroll
        for (int j = 0; j < 8; ++j)
            d[j] = dist * __builtin_amdgcn_rcpf(den0 + nxu[j]);
        float* row = op + (size_t)i * WOUT;           // 32B-aligned
        f4 v0 = (f4){d[0], d[1], d[2], d[3]};
        f4 v1 = (f4){d[4], d[5], d[6], d[7]};
        __builtin_nontemporal_store(v0, reinterpret_cast<f4*>(row));
        __builtin_nontemporal_store(v1, reinterpret_cast<f4*>(row + 4));
    }
    }  // rep
}

extern "C" void kernel_launch(void* const* d_in, const int* in_sizes, int n_in,
                              void* d_out, int out_size, void* d_ws, size_t ws_size,
                              hipStream_t stream) {
    const float* x  = (const float*)d_in[0];
    const float* w0 = (const float*)d_in[1];  const float* b0 = (const float*)d_in[2];
    const float* w1 = (const float*)d_in[3];  const float* b1 = (const float*)d_in[4];
    const float* w2 = (const float*)d_in[5];  const float* b2 = (const float*)d_in[6];
    const float* w3 = (const float*)d_in[7];  const float* b3 = (const float*)d_in[8];
    const float* w4 = (const float*)d_in[9];  const float* b4 = (const float*)d_in[10];
    const float* wc = (const float*)d_in[11]; const float* bc = (const float*)d_in[12];
    ushort_t* ws = (ushort_t*)d_ws;            // 22,528 B used
    float* out = (float*)d_out;

    hipLaunchKernelGGL(prep_w, dim3((NWT + 255) / 256), dim3(256), 0, stream,
                       w0, w1, w2, ws);
    hipLaunchKernelGGL(lpg32, dim3(NPOS / 128), dim3(256), 0, stream,
                       x, ws, b0, b1, b2, b3, w3, w4, b4, wc, bc, out);
}

// Round 11
// 121.626 us; speedup vs baseline: 1.6178x; 1.6178x over previous
//
#include <hip/hip_runtime.h>
#include <hip/hip_bf16.h>

// Problem geometry
#define NB   16
#define C0   128
#define HH   44
#define WW   144
#define HW   (HH * WW)        // 6336
#define NPOS (NB * HW)        // 101376
#define SC   8
#define WOUT (WW * SC)        // 1152
#define HOUT (HH * SC)        // 352
#define PI_F 3.1415926535f

typedef __attribute__((ext_vector_type(8)))  short bf8;   // 8 bf16 (A/B frag, 4 VGPR)
typedef __attribute__((ext_vector_type(4)))  float f4;
typedef __attribute__((ext_vector_type(16))) float f16v;  // 32x32 C/D frag (16 AGPR)
typedef unsigned short ushort_t;

// frag-exact bf16 weight layout in ws (ushort elements), 32x32x16 B-frags:
//   conv0: 16 chunks (t*8+s) x [64 lanes][8]   -> 8192
//   conv1:  4 chunks (s)     x [64 lanes][8]   -> 2048
//   conv2:  2 chunks (s)     x [64 lanes][8]   -> 1024  (N padded 16->32, zeros)
#define F0 0
#define F1 8192
#define F2 10240
#define NWT 11264

__device__ __forceinline__ unsigned f2bf(float f) {
    union { float f; unsigned u; } v; v.f = f;
    unsigned r = v.u + 0x7FFFu + ((v.u >> 16) & 1u);     // RNE
    return r >> 16;
}
__device__ __forceinline__ float eluf(float x) {
    return x > 0.f ? x : (__expf(x) - 1.f);
}
__device__ __forceinline__ float sigmoidf(float x) {
    return 1.f / (1.f + __expf(-x));
}
// C/D row map for 32x32 MFMA: reg r, k-group g -> position row
__device__ __forceinline__ int crow(int r, int g) {
    return (r & 3) + 8 * (r >> 2) + 4 * g;
}

// ---- prep: pack w0/w1/w2 into 32x32x16 B-fragment order (bf16) ----
__global__ void prep_w(const float* __restrict__ w0, const float* __restrict__ w1,
                       const float* __restrict__ w2, ushort_t* __restrict__ ws) {
    int i = blockIdx.x * 256 + (int)threadIdx.x;
    int j = i & 7, lane = (i >> 3) & 63;
    int n = lane & 31, g = lane >> 5;
    if (i < 8192) {
        int c = i >> 9;                       // c = t*8 + s
        int s = c & 7, t = c >> 3;
        ws[F0 + i] = (ushort_t)f2bf(w0[(t * 32 + n) * 128 + s * 16 + g * 8 + j]);
    } else if (i < 10240) {
        int i2 = i - 8192;
        int s = i2 >> 9;                      // 0..3
        ws[F1 + i2] = (ushort_t)f2bf(w1[n * 64 + s * 16 + g * 8 + j]);
    } else if (i < NWT) {
        int i2 = i - 10240;
        int s = i2 >> 9;                      // 0..1
        ws[F2 + i2] = (n < 16) ? (ushort_t)f2bf(w2[n * 32 + s * 16 + g * 8 + j])
                               : (ushort_t)0;
    }
}

// One wave = 32 consecutive positions via 32x32x16 bf16 MFMA.
// x loads: per instr 2 channels x 32 consecutive pos = 2 FULL 128B lines.
// conv0 (16 MFMA) -> LDS RT -> conv1 (4) -> LDS RT -> conv2 (2, N-padded)
// -> VALU tail redundant x2 (lane g handles output rows 4g..4g+3).
// B-frags from pre-packed global ws (L2-resident). No barriers.
// Stores are CACHED (r10 counters: nontemporal 16B half-line stores caused
// 2.4x WRITE_SIZE amplification at HBM).
__global__ __launch_bounds__(256, 4)
void lpg32(const float* __restrict__ x, const ushort_t* __restrict__ wsb,
           const float* __restrict__ b0, const float* __restrict__ b1,
           const float* __restrict__ b2, const float* __restrict__ b3,
           const float* __restrict__ w3, const float* __restrict__ w4,
           const float* __restrict__ b4,
           const float* __restrict__ wc, const float* __restrict__ bc,
           float* __restrict__ out) {
    __shared__ __align__(16) ushort_t hb1s[4][2304];   // [pos32][64+8] bf16
    __shared__ __align__(16) ushort_t hb2s[4][1280];   // [pos32][32+8] bf16
    __shared__ __align__(16) float    hb3s[4][640];    // [pos32][16+4] fp32

    const int tid  = (int)threadIdx.x;
    const int lane = tid & 63;
    const int wid  = tid >> 6;
    const int m    = lane & 31;          // position-in-tile / C-col channel
    const int g    = lane >> 5;          // k-group 0/1

    const int pm  = blockIdx.x * 128 + wid * 32 + m;   // this lane's position
    const int bm  = pm / HW;
    const int hwm = pm - bm * HW;
    const float* xb = x + (size_t)bm * (C0 * HW) + hwm;

    // ---- conv0: 128 -> 64, A loaded per K-step (8 ch), 2 N-tiles x 8 K ----
    bf8 A[8];
#pragma unroll
    for (int s = 0; s < 8; ++s) {
        float xr[8];
#pragma unroll
        for (int j = 0; j < 8; ++j)
            xr[j] = xb[(s * 16 + g * 8 + j) * HW];     // 2 full lines / instr
        bf8 a;
#pragma unroll
        for (int j = 0; j < 8; j += 2) {
            __hip_bfloat162 pck = __float22bfloat162_rn(make_float2(xr[j], xr[j + 1]));
            union { __hip_bfloat162 b; short s2[2]; } u; u.b = pck;
            a[j] = u.s2[0]; a[j + 1] = u.s2[1];
        }
        A[s] = a;
    }

    f16v acc0, acc1;
    {
        const float bb0 = b0[m], bb1 = b0[32 + m];
#pragma unroll
        for (int r = 0; r < 16; ++r) { acc0[r] = bb0; acc1[r] = bb1; }
    }
#pragma unroll
    for (int s = 0; s < 8; ++s) {
        bf8 B = *(const bf8*)(wsb + F0 + (0 * 8 + s) * 512 + lane * 8);
        acc0 = __builtin_amdgcn_mfma_f32_32x32x16_bf16(A[s], B, acc0, 0, 0, 0);
    }
#pragma unroll
    for (int s = 0; s < 8; ++s) {
        bf8 B = *(const bf8*)(wsb + F0 + (1 * 8 + s) * 512 + lane * 8);
        acc1 = __builtin_amdgcn_mfma_f32_32x32x16_bf16(A[s], B, acc1, 0, 0, 0);
    }

    // ELU + scatter C-layout -> h1[pos][ch] bf16 (ch = t*32 + m, row = crow)
    ushort_t* h1p = &hb1s[wid][0];
#pragma unroll
    for (int r = 0; r < 16; ++r) {
        const int row = crow(r, g);
        h1p[row * 72 + m]      = (ushort_t)f2bf(eluf(acc0[r]));
        h1p[row * 72 + 32 + m] = (ushort_t)f2bf(eluf(acc1[r]));
    }

    // ---- conv1: 64 -> 32, 4 K-steps ----
    bf8 A1[4];
#pragma unroll
    for (int s = 0; s < 4; ++s)
        A1[s] = *(const bf8*)(h1p + m * 72 + s * 16 + g * 8);
    f16v c1;
    {
        const float bb = b1[m];
#pragma unroll
        for (int r = 0; r < 16; ++r) c1[r] = bb;
    }
#pragma unroll
    for (int s = 0; s < 4; ++s) {
        bf8 B = *(const bf8*)(wsb + F1 + s * 512 + lane * 8);
        c1 = __builtin_amdgcn_mfma_f32_32x32x16_bf16(A1[s], B, c1, 0, 0, 0);
    }
    ushort_t* h2p = &hb2s[wid][0];
#pragma unroll
    for (int r = 0; r < 16; ++r)
        h2p[crow(r, g) * 40 + m] = (ushort_t)f2bf(eluf(c1[r]));

    // ---- conv2: 32 -> 16 (N padded to 32; cols 16..31 are zero-weight) ----
    bf8 A2[2];
#pragma unroll
    for (int s = 0; s < 2; ++s)
        A2[s] = *(const bf8*)(h2p + m * 40 + s * 16 + g * 8);
    f16v c2;
    {
        const float bb = (m < 16) ? b2[m & 15] : 0.f;
#pragma unroll
        for (int r = 0; r < 16; ++r) c2[r] = bb;
    }
#pragma unroll
    for (int s = 0; s < 2; ++s) {
        bf8 B = *(const bf8*)(wsb + F2 + s * 512 + lane * 8);
        c2 = __builtin_amdgcn_mfma_f32_32x32x16_bf16(A2[s], B, c2, 0, 0, 0);
    }
    float* h3p = &hb3s[wid][0];
    if (m < 16) {
#pragma unroll
        for (int r = 0; r < 16; ++r)
            h3p[crow(r, g) * 20 + m] = eluf(c2[r]);
    }

    // ---- tail: lane handles pos m (2x redundant across g) ----
    float h3[16];
#pragma unroll
    for (int i = 0; i < 4; ++i) {
        f4 v = *(const f4*)(h3p + m * 20 + i * 4);
        h3[4 * i + 0] = v[0]; h3[4 * i + 1] = v[1];
        h3[4 * i + 2] = v[2]; h3[4 * i + 3] = v[3];
    }

    float h4v[8];
#pragma unroll
    for (int o = 0; o < 8; ++o) {
        float a = b3[o];                              // uniform -> s_load
#pragma unroll
        for (int c = 0; c < 16; ++c) a = fmaf(h3[c], w3[o * 16 + c], a);
        h4v[o] = eluf(a);
    }
    float h5v[4];
#pragma unroll
    for (int o = 0; o < 4; ++o) {
        float a = b4[o];
#pragma unroll
        for (int c = 0; c < 8; ++c) a = fmaf(h4v[c], w4[o * 8 + c], a);
        h5v[o] = a;                                   // no activation
    }
    float y0 = bc[0], y1 = bc[1], y2 = bc[2];
#pragma unroll
    for (int c = 0; c < 4; ++c) {
        y0 = fmaf(h5v[c], wc[0 * 4 + c], y0);
        y1 = fmaf(h5v[c], wc[1 * 4 + c], y1);
        y2 = fmaf(h5v[c], wc[2 * 4 + c], y2);
    }

    const float theta = sigmoidf(y0) * (PI_F / 6.0f);
    const float phi   = sigmoidf(y1) * (PI_F * 2.0f);
    const float dist  = sigmoidf(y2) * 81.0f;
    const float st = __sinf(theta), ct = __cosf(theta);
    const float sp = __sinf(phi),   cp = __cosf(phi);
    float nx = st * cp, ny = st * sp, nz = ct;
    const float inv = rsqrtf(fmaxf(nx * nx + ny * ny + nz * nz, 1e-24f));
    nx *= inv; ny *= inv; nz *= inv;

    // ---- 8x8 upsample: lane g writes rows 4g..4g+3 of its position ----
    const int hh = hwm / WW;
    const int wp = hwm - hh * WW;
    float* op = out + ((size_t)bm * HOUT + (size_t)hh * SC) * WOUT + (size_t)wp * SC;

    float nxu[8];
#pragma unroll
    for (int j = 0; j < 8; ++j) nxu[j] = nx * ((j - 3.5f) * 0.125f);

#pragma unroll
    for (int ii = 0; ii < 4; ++ii) {
        const int i = g * 4 + ii;
        const float den0 = fmaf(ny, (i - 3.5f) * 0.125f, nz);
        float d[8];
#pragma unroll
        for (int j = 0; j < 8; ++j)
            d[j] = dist * __builtin_amdgcn_rcpf(den0 + nxu[j]);
        float* row = op + (size_t)i * WOUT;           // 32B-aligned
        *reinterpret_cast<f4*>(row)     = (f4){d[0], d[1], d[2], d[3]};
        *reinterpret_cast<f4*>(row + 4) = (f4){d[4], d[5], d[6], d[7]};
    }
}

extern "C" void kernel_launch(void* const* d_in, const int* in_sizes, int n_in,
                              void* d_out, int out_size, void* d_ws, size_t ws_size,
                              hipStream_t stream) {
    const float* x  = (const float*)d_in[0];
    const float* w0 = (const float*)d_in[1];  const float* b0 = (const float*)d_in[2];
    const float* w1 = (const float*)d_in[3];  const float* b1 = (const float*)d_in[4];
    const float* w2 = (const float*)d_in[5];  const float* b2 = (const float*)d_in[6];
    const float* w3 = (const float*)d_in[7];  const float* b3 = (const float*)d_in[8];
    const float* w4 = (const float*)d_in[9];  const float* b4 = (const float*)d_in[10];
    const float* wc = (const float*)d_in[11]; const float* bc = (const float*)d_in[12];
    ushort_t* ws = (ushort_t*)d_ws;            // 22,528 B used
    float* out = (float*)d_out;

    hipLaunchKernelGGL(prep_w, dim3((NWT + 255) / 256), dim3(256), 0, stream,
                       w0, w1, w2, ws);
    hipLaunchKernelGGL(lpg32, dim3(NPOS / 128), dim3(256), 0, stream,
                       x, ws, b0, b1, b2, b3, w3, w4, b4, wc, bc, out);
}